// Round 1
// baseline (108.311 us; speedup 1.0000x reference)
//
#include <hip/hip_runtime.h>
#include <hip/hip_bf16.h>

// DendriticLayerSiLU: out = silu(softmax-gated template proj) * (x @ W^T)
// N=4096 tokens, K=2048, H=1024, 32 windows of 64.
// Dual-GEMM, fused online window softmax. lin path bf16x3, gate path bf16.

typedef __attribute__((ext_vector_type(8))) short short8;
typedef __attribute__((ext_vector_type(4))) float f32x4;

#define N_TOK 4096
#define K_DIM 2048
#define H_DIM 1024
#define BM 128
#define BH 128
#define BK 32
#define NITER 64            // K_DIM / BK
#define LDSZ (BM * BK)      // shorts per LDS sub-array

__device__ __forceinline__ unsigned short f2bf(float f) {
    unsigned int u = __float_as_uint(f);
    u += 0x7FFFu + ((u >> 16) & 1u);    // round-to-nearest-even
    return (unsigned short)(u >> 16);
}
__device__ __forceinline__ float bf2f(unsigned short h) {
    return __uint_as_float(((unsigned int)h) << 16);
}

__device__ __forceinline__ void cvt_split(f32x4 a, f32x4 b, short8& vh, short8& vl) {
#pragma unroll
    for (int i = 0; i < 4; ++i) {
        float f = a[i];
        unsigned short h = f2bf(f);
        vh[i] = (short)h;
        vl[i] = (short)f2bf(f - bf2f(h));
    }
#pragma unroll
    for (int i = 0; i < 4; ++i) {
        float f = b[i];
        unsigned short h = f2bf(f);
        vh[i + 4] = (short)h;
        vl[i + 4] = (short)f2bf(f - bf2f(h));
    }
}
__device__ __forceinline__ short8 cvt_hi(f32x4 a, f32x4 b) {
    short8 v;
#pragma unroll
    for (int i = 0; i < 4; ++i) { v[i] = (short)f2bf(a[i]); v[i + 4] = (short)f2bf(b[i]); }
    return v;
}

#define MFMA16(A, B, C) __builtin_amdgcn_mfma_f32_16x16x32_bf16(A, B, C, 0, 0, 0)

__global__ __launch_bounds__(512) void dend_fused(
    const float* __restrict__ X,   // [4096][2048]
    const float* __restrict__ T,   // [1024][2048] templates
    const float* __restrict__ W,   // [1024][2048] weights
    float* __restrict__ O)         // [4096][1024]
{
    // LDS arrays: 0=x_hi 1=x_lo 2=w_hi 3=w_lo 4=t_hi ; double buffered = 80 KB
    __shared__ __align__(16) short lds[2][5][LDSZ];

    const int tid  = threadIdx.x;
    const int lane = tid & 63;
    const int wv   = tid >> 6;    // 0..7
    const int wm   = wv >> 2;     // 0..1  (64 tokens each)
    const int wn   = wv & 3;      // 0..3  (32 units each)

    // XCD-chunked swizzle: round-robin bid%8 -> each XCD owns one H-panel
    const int bid     = blockIdx.x;
    const int logical = (bid & 7) * 32 + (bid >> 3);
    const int hb   = logical >> 5;   // 0..7
    const int nb   = logical & 31;   // 0..31
    const int row0 = nb * BM;
    const int col0 = hb * BH;

    // ---- staging mapping: thread -> (row, 8-float chunk), XOR slot swizzle
    const int srow  = tid >> 2;                    // 0..127
    const int schn  = tid & 3;                     // 0..3
    const int sslot = schn ^ ((srow >> 1) & 3);
    const int swoff = srow * BK + sslot * 8;       // short index, 16B aligned

    const float* gx = X + (size_t)(row0 + srow) * K_DIM + schn * 8;
    const float* gw = W + (size_t)(col0 + srow) * K_DIM + schn * 8;
    const float* gt = T + (size_t)(col0 + srow) * K_DIM + schn * 8;

    // ---- fragment read offsets (fixed per thread; swizzled)
    const int g = lane >> 4;
    int a_off[4], b_off[2];
#pragma unroll
    for (int mi = 0; mi < 4; ++mi) {
        int r = wm * 64 + mi * 16 + (lane & 15);
        a_off[mi] = r * BK + (g ^ ((r >> 1) & 3)) * 8;
    }
#pragma unroll
    for (int nj = 0; nj < 2; ++nj) {
        int r = wn * 32 + nj * 16 + (lane & 15);
        b_off[nj] = r * BK + (g ^ ((r >> 1) & 3)) * 8;
    }

    const f32x4 zeroc = (f32x4)0.0f;
    f32x4 lin[4][2], num[4][2], den[4][2], win[4][2];
#pragma unroll
    for (int mi = 0; mi < 4; ++mi)
#pragma unroll
        for (int nj = 0; nj < 2; ++nj) {
            lin[mi][nj] = zeroc; num[mi][nj] = zeroc; den[mi][nj] = zeroc;
        }

    f32x4 rx0, rx1, rw0, rw1, rt0, rt1;

#define LOADS(t) do {                                                   \
        const float* px = gx + (size_t)(t) * BK;                        \
        const float* pw = gw + (size_t)(t) * BK;                        \
        const float* pt = gt + (size_t)(t) * BK;                        \
        rx0 = *(const f32x4*)(px); rx1 = *(const f32x4*)(px + 4);       \
        rw0 = *(const f32x4*)(pw); rw1 = *(const f32x4*)(pw + 4);       \
        rt0 = *(const f32x4*)(pt); rt1 = *(const f32x4*)(pt + 4);       \
    } while (0)

#define WRITE(buf) do {                                                 \
        short8 vh, vl;                                                  \
        cvt_split(rx0, rx1, vh, vl);                                    \
        *(short8*)&lds[buf][0][swoff] = vh;                             \
        *(short8*)&lds[buf][1][swoff] = vl;                             \
        cvt_split(rw0, rw1, vh, vl);                                    \
        *(short8*)&lds[buf][2][swoff] = vh;                             \
        *(short8*)&lds[buf][3][swoff] = vl;                             \
        *(short8*)&lds[buf][4][swoff] = cvt_hi(rt0, rt1);               \
    } while (0)

#define COMPUTE(buf, ZW) do {                                           \
        short8 bwh[2], bwl[2], bth[2];                                  \
        _Pragma("unroll")                                               \
        for (int nj = 0; nj < 2; ++nj) {                                \
            bwh[nj] = *(const short8*)&lds[buf][2][b_off[nj]];          \
            bwl[nj] = *(const short8*)&lds[buf][3][b_off[nj]];          \
            bth[nj] = *(const short8*)&lds[buf][4][b_off[nj]];          \
        }                                                               \
        _Pragma("unroll")                                               \
        for (int mi = 0; mi < 4; ++mi) {                                \
            short8 ah = *(const short8*)&lds[buf][0][a_off[mi]];        \
            short8 al = *(const short8*)&lds[buf][1][a_off[mi]];        \
            _Pragma("unroll")                                           \
            for (int nj = 0; nj < 2; ++nj) {                            \
                lin[mi][nj] = MFMA16(ah, bwh[nj], lin[mi][nj]);         \
                lin[mi][nj] = MFMA16(al, bwh[nj], lin[mi][nj]);         \
                lin[mi][nj] = MFMA16(ah, bwl[nj], lin[mi][nj]);         \
                win[mi][nj] = MFMA16(ah, bth[nj], (ZW) ? zeroc : win[mi][nj]); \
            }                                                           \
        }                                                               \
    } while (0)

#define EPILOG() do {                                                   \
        _Pragma("unroll")                                               \
        for (int mi = 0; mi < 4; ++mi)                                  \
        _Pragma("unroll")                                               \
        for (int nj = 0; nj < 2; ++nj)                                  \
        _Pragma("unroll")                                               \
        for (int i = 0; i < 4; ++i) {                                   \
            float d = win[mi][nj][i];                                   \
            float e = __expf(fabsf(d));                                 \
            den[mi][nj][i] += e;                                        \
            num[mi][nj][i] = fmaf(e, d, num[mi][nj][i]);                \
        }                                                               \
    } while (0)

    // ---- prologue: stage tile 0 into buf 0
    LOADS(0);
    WRITE(0);
    __syncthreads();

#pragma unroll 1
    for (int w = 0; w < 32; ++w) {
        const int t0 = 2 * w;
        // sub-step 0: compute buf0 (window start, zero C), prefetch t0+1 -> buf1
        LOADS(t0 + 1);
        COMPUTE(0, true);
        __syncthreads();
        WRITE(1);
        __syncthreads();
        // sub-step 1: compute buf1 (window finish), epilogue, prefetch -> buf0
        const bool more = (w < 31);
        if (more) LOADS(t0 + 2);
        COMPUTE(1, false);
        EPILOG();
        __syncthreads();
        if (more) WRITE(0);
        __syncthreads();
    }

    // ---- final epilogue: g = num/den, silu, multiply, store
#pragma unroll
    for (int mi = 0; mi < 4; ++mi)
#pragma unroll
        for (int nj = 0; nj < 2; ++nj)
#pragma unroll
            for (int i = 0; i < 4; ++i) {
                float gg   = num[mi][nj][i] / den[mi][nj][i];
                float gate = gg / (1.0f + __expf(-gg));
                float val  = gate * lin[mi][nj][i];
                int r = row0 + wm * 64 + mi * 16 + (lane >> 4) * 4 + i;
                int c = col0 + wn * 32 + nj * 16 + (lane & 15);
                O[(size_t)r * H_DIM + c] = val;
            }
}

extern "C" void kernel_launch(void* const* d_in, const int* in_sizes, int n_in,
                              void* d_out, int out_size, void* d_ws, size_t ws_size,
                              hipStream_t stream) {
    const float* X = (const float*)d_in[0];   // x [4096,2048]
    const float* T = (const float*)d_in[1];   // template_flat [1024,2048]
    const float* W = (const float*)d_in[2];   // weights [1024,2048]
    float* O = (float*)d_out;                 // [4096,1024]
    (void)in_sizes; (void)n_in; (void)out_size; (void)d_ws; (void)ws_size;

    dim3 grid(32 * 8);   // 256 blocks = 1/CU, 128x128 tiles
    dim3 block(512);
    hipLaunchKernelGGL(dend_fused, grid, block, 0, stream, X, T, W, O);
}